// Round 20
// baseline (135.102 us; speedup 1.0000x reference)
//
#include <hip/hip_runtime.h>
#include <hip/hip_bf16.h>

#define N_SUP 16384
#define M_Q   4096
#define TV    27
#define CIN   41
#define CINP  44          // padded LDS stride (176 B, 16B-aligned rows)
#define CH1   864
#define CH2   128
#define CAP   1024
#define NB    12          // bins per xy axis (width 50/12 = 4.17 >= 4)
#define NSL   9           // candidate-scan slices per voxel (27*9 = 243 threads)

// kC split-K tiling: 32x128 tile, 4x4/thread, BK=24, 4 K-chunks of 216 -> grid 512
#define KC_BK  24
#define KC_KS  216
#define KC_NCH 4

// grid offset value for axis-index 0/1/2 : linspace(-R+R/NV, R-R/NV, 3) = {-1.3333334, 0, +1.3333334}
__device__ __forceinline__ float gsel(int i){
  const float GOFF = (float)(-2.0 + 2.0 / 3.0);   // -1.3333334f (matches f32 linspace endpoint)
  return (i == 0) ? GOFF : ((i == 2) ? -GOFF : 0.0f);
}

__device__ __forceinline__ int binOf(float x){
  int b = (int)(x * (float)(NB / 50.0));
  return (b < 0) ? 0 : ((b > NB - 1) ? NB - 1 : b);
}

// branchless 3-deep insert of u64 key (keeps k0 <= k1 <= k2)
__device__ __forceinline__ void insK(unsigned long long key,
                                     unsigned long long& k0,
                                     unsigned long long& k1,
                                     unsigned long long& k2){
  bool b0 = key < k0, b1 = key < k1, b2 = key < k2;
  k2 = b1 ? k1 : (b2 ? key : k2);
  k1 = b0 ? k0 : (b1 ? key : k1);
  k0 = b0 ? key : k0;
}

// ---------------- Kernel Pre: w1/w2 transpose + support-point bin count (fused) ----------------
__global__ void kPre(const float* __restrict__ w1, float* __restrict__ w1T,
                     const float* __restrict__ w2, float* __restrict__ w2T,
                     const float* __restrict__ sup_xyz, int* __restrict__ counts)
{
  int idx = blockIdx.x * 256 + threadIdx.x;
  if (idx < N_SUP) {
    float x = sup_xyz[3*idx], y = sup_xyz[3*idx+1];
    atomicAdd(&counts[binOf(x) * NB + binOf(y)], 1);
  }
  if (idx < CIN * CH1) {
    int k = idx / CH1, t = idx % CH1;
    w1T[idx] = w1[(size_t)t * CIN + k];
  }
  int j = idx - CIN * CH1;
  if (j >= 0 && j < CH1 * CH2) {
    int k = j / CH2, c = j % CH2;
    w2T[j] = w2[(size_t)c * CH1 + k];
  }
}

__global__ void kScan(const int* __restrict__ counts, int* __restrict__ starts, int* __restrict__ cursor)
{
  __shared__ int sc[NB*NB];
  int t = threadIdx.x;
  if (t < NB*NB) sc[t] = counts[t];
  __syncthreads();
  if (t == 0) {
    int acc = 0;
    for (int b = 0; b < NB*NB; b++) { int c = sc[b]; sc[b] = acc; acc += c; }
  }
  __syncthreads();
  if (t < NB*NB) { starts[t] = sc[t]; cursor[t] = sc[t]; }
  if (t == NB*NB) starts[NB*NB] = N_SUP;
}

__global__ void kScatter(const float* __restrict__ sup_xyz, int* __restrict__ cursor,
                         float4* __restrict__ pxyzs)
{
  int i = blockIdx.x * 256 + threadIdx.x;
  if (i < N_SUP) {
    float x = sup_xyz[3*i], y = sup_xyz[3*i+1], z = sup_xyz[3*i+2];
    int b = binOf(x) * NB + binOf(y);
    int p = atomicAdd(&cursor[b], 1);
    pxyzs[p] = make_float4(x, y, z, __uint_as_float((unsigned)i));
  }
}

// ---------------- Kernel A12: bin-pruned cube filter + per-voxel 3NN (guarded insert) ----------------
// Phase 2a: each thread runs TWO independent top-3 chains (even/odd slice-steps) to break
// the loop-carried k2df->insert dependency; in-register merge at the end. Selection exact:
// top-3 of a union is contained in the union of per-subset top-3s; keys are exact (dd,sid).
__global__ __launch_bounds__(256) void kA12(const float4* __restrict__ pxyzs,
                                            const int*   __restrict__ starts,
                                            const float* __restrict__ new_xyz,
                                            float* __restrict__ nnD,
                                            int*   __restrict__ nnGI)
{
  __shared__ float4 cxyz[CAP];                 // filtered candidates (.w = sid bits)
  __shared__ unsigned long long sk[TV][NSL][3];
  __shared__ int s_cnt;

  const int m   = blockIdx.x;
  const int tid = threadIdx.x;
  if (tid == 0) s_cnt = 0;
  __syncthreads();

  const float qx = new_xyz[m*3+0];
  const float qy = new_xyz[m*3+1];
  const float qz = new_xyz[m*3+2];

  // ---- phase 1: cube filter over <=3x3 bins (z-test vacuous: |dz|<4 always) ----
  const int bx0 = binOf(qx - 4.0f), bx1 = binOf(qx + 4.0f);
  const int by0 = binOf(qy - 4.0f), by1 = binOf(qy + 4.0f);
  for (int bx = bx0; bx <= bx1; bx++) {
    const int beg = starts[bx * NB + by0];
    const int end = starts[bx * NB + by1 + 1];
    for (int i = beg + tid; i < end; i += 256) {
      float4 pt = pxyzs[i];
      if (fabsf(__fsub_rn(pt.x, qx)) <= 4.0f && fabsf(__fsub_rn(pt.y, qy)) <= 4.0f) {
        int p = atomicAdd(&s_cnt, 1);
        if (p < CAP) cxyz[p] = pt;
      }
    }
  }
  __syncthreads();
  const int cnt = (s_cnt < CAP) ? s_cnt : CAP;

  // ---- phase 2a: strided scan, 9 threads per voxel, two independent chains per thread ----
  const int v = tid / NSL, j = tid % NSL;      // 243 active threads
  if (v < TV) {
    const float gx = qx + gsel(v / 9);
    const float gy = qy + gsel((v / 3) % 3);
    const float gz = qz + gsel(v % 3);

    unsigned long long a0 = ~0ull, a1 = ~0ull, a2 = ~0ull;   // chain A
    unsigned long long b0 = ~0ull, b1 = ~0ull, b2 = ~0ull;   // chain B
    float a2df = __uint_as_float(0xFFFFFFFFu);   // NaN sentinels
    float b2df = __uint_as_float(0xFFFFFFFFu);

    for (int c = j; c < cnt; c += 2*NSL) {
      // chain A: candidate c
      {
        float4 f4 = cxyz[c];
        float dx = __fsub_rn(gx, f4.x);
        float dy = __fsub_rn(gy, f4.y);
        float dz = __fsub_rn(gz, f4.z);
        // forbid FMA contraction: must match numpy f32 (mul, mul, add, mul, add)
        float dd = __fadd_rn(__fadd_rn(__fmul_rn(dx,dx), __fmul_rn(dy,dy)), __fmul_rn(dz,dz));
        if (!(dd > a2df)) {
          unsigned long long key = ((unsigned long long)__float_as_uint(dd) << 32)
                                 | (unsigned long long)__float_as_uint(f4.w);
          insK(key, a0, a1, a2);
          a2df = __uint_as_float((unsigned)(a2 >> 32));
        }
      }
      // chain B: candidate c + NSL (independent of chain A)
      const int c2 = c + NSL;
      if (c2 < cnt) {
        float4 f4 = cxyz[c2];
        float dx = __fsub_rn(gx, f4.x);
        float dy = __fsub_rn(gy, f4.y);
        float dz = __fsub_rn(gz, f4.z);
        float dd = __fadd_rn(__fadd_rn(__fmul_rn(dx,dx), __fmul_rn(dy,dy)), __fmul_rn(dz,dz));
        if (!(dd > b2df)) {
          unsigned long long key = ((unsigned long long)__float_as_uint(dd) << 32)
                                 | (unsigned long long)__float_as_uint(f4.w);
          insK(key, b0, b1, b2);
          b2df = __uint_as_float((unsigned)(b2 >> 32));
        }
      }
    }
    // merge chain B into chain A (exact)
    insK(b0, a0, a1, a2);
    insK(b1, a0, a1, a2);
    insK(b2, a0, a1, a2);
    sk[v][j][0] = a0; sk[v][j][1] = a1; sk[v][j][2] = a2;
  }
  __syncthreads();

  // ---- phase 2b: merge 9x3 keys per voxel + dump (d,gi) (threads 0..26) ----
  if (tid < TV) {
    const int vv = tid;
    unsigned long long k0 = ~0ull, k1 = ~0ull, k2 = ~0ull;
    #pragma unroll
    for (int jj = 0; jj < NSL; jj++) {
      insK(sk[vv][jj][0], k0, k1, k2);
      insK(sk[vv][jj][1], k0, k1, k2);
      insK(sk[vv][jj][2], k0, k1, k2);
    }
    const int base = m * TV + vv;
    if (cnt > 0) {
      unsigned long long ks[3] = {k0, k1, k2};
      #pragma unroll
      for (int r = 0; r < 3; r++) {
        unsigned db = (unsigned)(ks[r] >> 32);
        bool ok = (db != 0xFFFFFFFFu);
        nnD[base*3+r]  = ok ? __uint_as_float(db) : 1e10f;
        nnGI[base*3+r] = ok ? (int)(unsigned)(ks[r] & 0xFFFFFFFFull) : 0;
      }
    } else {
      #pragma unroll
      for (int r = 0; r < 3; r++) { nnD[base*3+r] = -1.0f; nnGI[base*3+r] = 0; }
    }
  }
}

// ---------------- Kernel A3: weights + local_xyz + interp + conv1 (8 queries/block) + BN1 stats ----------------
__global__ __launch_bounds__(256) void kA3(const float* __restrict__ sup_feat,
                                           const float* __restrict__ sup_xyz,
                                           const float* __restrict__ new_xyz,
                                           const float* __restrict__ nnD,
                                           const int*   __restrict__ nnGI,
                                           const float* __restrict__ w1T,
                                           float* __restrict__ y1,
                                           float* __restrict__ stats1)   // [8][2*CH1]
{
  __shared__ float s_feats[8][TV][CINP];  // 38,016 B (rows 16B-aligned)
  __shared__ float s_w[8][TV][3];
  __shared__ int   s_gi[8][TV][3];

  const int m0  = blockIdx.x * 8;
  const int tid = threadIdx.x;

  // per-(q,v) thread: weights + local_xyz (216 threads)
  if (tid < 8*TV) {
    const int q = tid / TV, vv = tid % TV;
    const int m = m0 + q;
    const int base = m * TV + vv;
    float d[3]; int gi[3];
    #pragma unroll
    for (int r = 0; r < 3; r++) { d[r] = nnD[base*3+r]; gi[r] = nnGI[base*3+r]; }
    #pragma unroll
    for (int r = 0; r < 3; r++) s_gi[q][vv][r] = gi[r];
    if (d[0] < 0.0f) {                           // empty query: zero weights + zero local
      #pragma unroll
      for (int r = 0; r < 3; r++) s_w[q][vv][r] = 0.0f;
      #pragma unroll
      for (int jj = 0; jj < 9; jj++) s_feats[q][vv][32 + jj] = 0.0f;
    } else {
      float r0 = 1.0f / (d[0] + 1e-8f);
      float r1 = 1.0f / (d[1] + 1e-8f);
      float r2 = 1.0f / (d[2] + 1e-8f);
      float den = fmaxf(r0 + r1 + r2, 1e-8f);
      s_w[q][vv][0] = r0 / den; s_w[q][vv][1] = r1 / den; s_w[q][vv][2] = r2 / den;
      const float gx = new_xyz[m*3+0] + gsel(vv / 9);
      const float gy = new_xyz[m*3+1] + gsel((vv / 3) % 3);
      const float gz = new_xyz[m*3+2] + gsel(vv % 3);
      #pragma unroll
      for (int r = 0; r < 3; r++) {
        bool ok = (d[r] != 1e10f);
        s_feats[q][vv][32 + r*3 + 0] = ok ? (gx - sup_xyz[gi[r]*3 + 0]) : 0.0f;
        s_feats[q][vv][32 + r*3 + 1] = ok ? (gy - sup_xyz[gi[r]*3 + 1]) : 0.0f;
        s_feats[q][vv][32 + r*3 + 2] = ok ? (gz - sup_xyz[gi[r]*3 + 2]) : 0.0f;
      }
    }
  }
  __syncthreads();

  // interp, float4: 8*27*8 = 1728 float4 elements
  const float4* sf4 = (const float4*)sup_feat;
  for (int t = tid; t < 8*TV*8; t += 256) {
    const int q = t / (TV*8), rem = t % (TV*8);
    const int v = rem >> 3, g = rem & 7;        // 8 float4 groups = 32 channels
    float4 a = sf4[s_gi[q][v][0]*8 + g];
    float4 b = sf4[s_gi[q][v][1]*8 + g];
    float4 c = sf4[s_gi[q][v][2]*8 + g];
    float w0 = s_w[q][v][0], w1_ = s_w[q][v][1], w2_ = s_w[q][v][2];
    float4 o;
    o.x = w0*a.x + w1_*b.x + w2_*c.x;
    o.y = w0*a.y + w1_*b.y + w2_*c.y;
    o.z = w0*a.z + w1_*b.z + w2_*c.z;
    o.w = w0*a.w + w1_*b.w + w2_*c.w;
    *(float4*)&s_feats[q][v][g*4] = o;
  }
  __syncthreads();

  const int copy = (blockIdx.x & 7) * 2 * CH1;   // spread stat atomics over 8 copies
  for (int t = tid; t < CH1; t += 256) {
    const int v = t >> 5;
    float acc[8];
    #pragma unroll
    for (int q = 0; q < 8; q++) acc[q] = 0.0f;
    for (int k = 0; k < CIN; k++) {
      float w = w1T[k * CH1 + t];
      #pragma unroll
      for (int q = 0; q < 8; q++) acc[q] += s_feats[q][v][k] * w;
    }
    float s = 0.0f, ss = 0.0f;
    #pragma unroll
    for (int q = 0; q < 8; q++) {
      y1[(size_t)(m0 + q) * CH1 + t] = acc[q];
      s += acc[q]; ss += acc[q] * acc[q];
    }
    atomicAdd(&stats1[copy + t],       s);
    atomicAdd(&stats1[copy + CH1 + t], ss);
  }
}

// ---------------- Kernel C: BN1-fused split-K GEMM (kS fused), 32x128 tile, 4x4/thread, grid 512 ----------------
__global__ __launch_bounds__(256) void kC(const float* __restrict__ y1,
                                          const float* __restrict__ stats1,   // [8][2*CH1]
                                          const float* __restrict__ g1,
                                          const float* __restrict__ b1,
                                          const float* __restrict__ w2T,
                                          float* __restrict__ zpart)   // [4][M_Q][CH2]
{
  __shared__ float As[KC_BK][36];      // [k][row], stride 36 (144 B, 16B-aligned rows)
  __shared__ float Bs[KC_BK][CH2];     // 12 KB
  __shared__ float lsc[KC_KS], lsh[KC_KS];

  const int tid = threadIdx.x;
  const int mb  = blockIdx.x & 127;
  const int ch  = blockIdx.x >> 7;
  const int m0  = mb * 32;
  const int kb  = ch * KC_KS;

  // fused kS: BN1 scale/shift for this chunk's 216 channels (sums 8 stat copies)
  for (int t = tid; t < KC_KS; t += 256) {
    const int c = kb + t;
    float s = 0.0f, ssq = 0.0f;
    #pragma unroll
    for (int k = 0; k < 8; k++) {
      s   += stats1[k * 2 * CH1 + c];
      ssq += stats1[k * 2 * CH1 + CH1 + c];
    }
    float mu  = s  * (1.0f / M_Q);
    float var = ssq * (1.0f / M_Q) - mu * mu;
    float r   = 1.0f / sqrtf(var + 1e-5f);
    float gg = g1[c];
    lsc[t] = r * gg;
    lsh[t] = b1[c] - mu * r * gg;
  }

  const int ar = tid >> 3;          // 0..31 A-tile row
  const int ac = (tid & 7) * 3;     // 0..21 A-tile k-offset (3 consecutive)
  const int ty = tid >> 5;          // 0..7  -> rows ty*4..+3
  const int tx = tid & 31;          // 0..31 -> cols tx*4..+3

  // prefetch tile 0
  float pa0, pa1, pa2; float4 pb[3];
  {
    const float* yr = &y1[(size_t)(m0 + ar) * CH1 + kb + ac];
    pa0 = yr[0]; pa1 = yr[1]; pa2 = yr[2];
    #pragma unroll
    for (int jj = 0; jj < 3; jj++) {
      int fid = tid + jj * 256; int kk = fid >> 5, c4 = (fid & 31) * 4;
      pb[jj] = *(const float4*)&w2T[(size_t)(kb + kk) * CH2 + c4];
    }
  }

  float acc[4][4];
  #pragma unroll
  for (int i = 0; i < 4; i++)
    #pragma unroll
    for (int jj = 0; jj < 4; jj++) acc[i][jj] = 0.0f;

  for (int kt = 0; kt < KC_KS / KC_BK; kt++) {
    __syncthreads();                       // previous tile consumed; covers lsc/lsh at kt=0
    const int kl = kt * KC_BK + ac;
    As[ac  ][ar] = fmaxf(pa0 * lsc[kl  ] + lsh[kl  ], 0.0f);
    As[ac+1][ar] = fmaxf(pa1 * lsc[kl+1] + lsh[kl+1], 0.0f);
    As[ac+2][ar] = fmaxf(pa2 * lsc[kl+2] + lsh[kl+2], 0.0f);
    #pragma unroll
    for (int jj = 0; jj < 3; jj++) {
      int fid = tid + jj * 256; int kk = fid >> 5, c4 = (fid & 31) * 4;
      *(float4*)&Bs[kk][c4] = pb[jj];
    }
    __syncthreads();
    if (kt + 1 < KC_KS / KC_BK) {          // prefetch next tile (overlaps compute)
      const float* yr = &y1[(size_t)(m0 + ar) * CH1 + kb + (kt+1) * KC_BK + ac];
      pa0 = yr[0]; pa1 = yr[1]; pa2 = yr[2];
      #pragma unroll
      for (int jj = 0; jj < 3; jj++) {
        int fid = tid + jj * 256; int kk = fid >> 5, c4 = (fid & 31) * 4;
        pb[jj] = *(const float4*)&w2T[(size_t)(kb + (kt+1) * KC_BK + kk) * CH2 + c4];
      }
    }
    #pragma unroll
    for (int kk = 0; kk < KC_BK; kk++) {
      float4 av = *(const float4*)&As[kk][ty*4];
      float4 bv = *(const float4*)&Bs[kk][tx*4];
      acc[0][0] += av.x*bv.x; acc[0][1] += av.x*bv.y; acc[0][2] += av.x*bv.z; acc[0][3] += av.x*bv.w;
      acc[1][0] += av.y*bv.x; acc[1][1] += av.y*bv.y; acc[1][2] += av.y*bv.z; acc[1][3] += av.y*bv.w;
      acc[2][0] += av.z*bv.x; acc[2][1] += av.z*bv.y; acc[2][2] += av.z*bv.z; acc[2][3] += av.z*bv.w;
      acc[3][0] += av.w*bv.x; acc[3][1] += av.w*bv.y; acc[3][2] += av.w*bv.z; acc[3][3] += av.w*bv.w;
    }
  }

  float* zp = zpart + (size_t)ch * M_Q * CH2;
  #pragma unroll
  for (int i = 0; i < 4; i++) {
    *(float4*)&zp[(size_t)(m0 + ty*4 + i) * CH2 + tx*4] =
        make_float4(acc[i][0], acc[i][1], acc[i][2], acc[i][3]);
  }
}

// ---------------- Kernel Z: sum split-K partials -> z, BN2 stats (grid 512) ----------------
__global__ void kZ(const float* __restrict__ zpart,
                   float* __restrict__ z,
                   float* __restrict__ stats2)   // [8][256]
{
  const int tid = threadIdx.x;
  const int c = tid & 127, h = tid >> 7;
  const int m0 = blockIdx.x * 8 + h * 4;
  float s = 0.0f, ss = 0.0f;
  for (int r = 0; r < 4; r++) {
    size_t off = (size_t)(m0 + r) * CH2 + c;
    float v = zpart[off]
            + zpart[off + (size_t)M_Q*CH2]
            + zpart[off + (size_t)2*M_Q*CH2]
            + zpart[off + (size_t)3*M_Q*CH2];
    z[off] = v;
    s += v; ss += v * v;
  }
  const int copy = (blockIdx.x & 7) * 256;
  atomicAdd(&stats2[copy + c],       s);
  atomicAdd(&stats2[copy + 128 + c], ss);
}

// ---------------- Kernel D: BN2 apply + ReLU -> f32 out (float4) ----------------
__global__ void kD(const float* __restrict__ z,
                   const float* __restrict__ stats2,   // [8][256]
                   const float* __restrict__ g2,
                   const float* __restrict__ b2,
                   float* __restrict__ out)
{
  int t4 = blockIdx.x * 256 + threadIdx.x;
  if (t4 >= M_Q * CH2 / 4) return;
  int c = (t4 & 31) * 4;
  float4 zv = *(const float4*)&z[(size_t)t4 * 4];
  float4 sv = make_float4(0,0,0,0), qv = make_float4(0,0,0,0);
  #pragma unroll
  for (int k = 0; k < 8; k++) {
    float4 a = *(const float4*)&stats2[k * 256 + c];
    float4 b = *(const float4*)&stats2[k * 256 + 128 + c];
    sv.x += a.x; sv.y += a.y; sv.z += a.z; sv.w += a.w;
    qv.x += b.x; qv.y += b.y; qv.z += b.z; qv.w += b.w;
  }
  float4 gv = *(const float4*)&g2[c];
  float4 bv = *(const float4*)&b2[c];
  float4 o;
  {
    float mu = sv.x * (1.0f/M_Q), var = qv.x * (1.0f/M_Q) - mu*mu;
    o.x = fmaxf((zv.x - mu) * (1.0f/sqrtf(var + 1e-5f)) * gv.x + bv.x, 0.0f);
  }
  {
    float mu = sv.y * (1.0f/M_Q), var = qv.y * (1.0f/M_Q) - mu*mu;
    o.y = fmaxf((zv.y - mu) * (1.0f/sqrtf(var + 1e-5f)) * gv.y + bv.y, 0.0f);
  }
  {
    float mu = sv.z * (1.0f/M_Q), var = qv.z * (1.0f/M_Q) - mu*mu;
    o.z = fmaxf((zv.z - mu) * (1.0f/sqrtf(var + 1e-5f)) * gv.z + bv.z, 0.0f);
  }
  {
    float mu = sv.w * (1.0f/M_Q), var = qv.w * (1.0f/M_Q) - mu*mu;
    o.w = fmaxf((zv.w - mu) * (1.0f/sqrtf(var + 1e-5f)) * gv.w + bv.w, 0.0f);
  }
  *(float4*)&out[(size_t)t4 * 4] = o;
}

extern "C" void kernel_launch(void* const* d_in, const int* in_sizes, int n_in,
                              void* d_out, int out_size, void* d_ws, size_t ws_size,
                              hipStream_t stream)
{
  const float* sup_xyz  = (const float*)d_in[0];
  const float* sup_feat = (const float*)d_in[1];
  const float* new_xyz  = (const float*)d_in[2];
  const float* w1       = (const float*)d_in[3];
  const float* g1       = (const float*)d_in[4];
  const float* b1       = (const float*)d_in[5];
  const float* w2       = (const float*)d_in[6];
  const float* g2       = (const float*)d_in[7];
  const float* b2       = (const float*)d_in[8];
  float* out = (float*)d_out;

  char* ws = (char*)d_ws;
  float*  y1     = (float*)(ws);                      // 14,155,776 B
  float*  z      = (float*)(ws + 14155776);           //  2,097,152 B (aliased by w1T early)
  float*  w2T    = (float*)(ws + 16252928);           //    442,368 B
  float*  stats1 = (float*)(ws + 16695296);           // 8 x 1728 f32 = 55,296 B
  float*  stats2 = (float*)(ws + 16750592);           // 8 x  256 f32 =  8,192 B
  int*    counts = (int*)  (ws + 16758784);           //        576 B
  int*    cursor = (int*)  (ws + 16759360);           //        576 B
  int*    starts = (int*)  (ws + 16759936);           //        580 B (pad to 16B)
  float4* pxyzs  = (float4*)(ws + 16760528);          //    262,144 B (16B-aligned)
  float*  nnD    = (float*)(ws + 17022672);           //  1,327,104 B
  int*    nnGI   = (int*)  (ws + 18349776);           //  1,327,104 B
  // zpart (4 x 2,097,152 B = 8,388,608 B) aliases nnD/nnGI (dead after kA3) and
  // extends past them; total ws footprint = 17,022,672 + 8,388,608 = 25,411,280 B.
  float*  zpart  = (float*)(ws + 17022672);
  // w1T (141,696 B) aliases z: kA3 (last reader) runs before kC/kZ touch z.
  float*  w1T    = z;

  // zero stats1 + stats2 + counts + cursor in one contiguous memset
  hipMemsetAsync(stats1, 0, 55296 + 8192 + 576 + 576, stream);

  const int PRE_TOT = CIN*CH1 + CH1*CH2;              // covers N_SUP too
  hipLaunchKernelGGL(kPre,    dim3((PRE_TOT + 255) / 256), dim3(256), 0, stream, w1, w1T, w2, w2T, sup_xyz, counts);
  hipLaunchKernelGGL(kScan,   dim3(1),                    dim3(256), 0, stream, counts, starts, cursor);
  hipLaunchKernelGGL(kScatter,dim3((N_SUP + 255) / 256),  dim3(256), 0, stream, sup_xyz, cursor, pxyzs);
  hipLaunchKernelGGL(kA12,    dim3(M_Q),                  dim3(256), 0, stream, pxyzs, starts, new_xyz, nnD, nnGI);
  hipLaunchKernelGGL(kA3,     dim3(M_Q / 8),              dim3(256), 0, stream, sup_feat, sup_xyz, new_xyz, nnD, nnGI, w1T, y1, stats1);
  hipLaunchKernelGGL(kC,      dim3(128 * KC_NCH),         dim3(256), 0, stream, y1, stats1, g1, b1, w2T, zpart);
  hipLaunchKernelGGL(kZ,      dim3(M_Q / 8),              dim3(256), 0, stream, zpart, z, stats2);
  hipLaunchKernelGGL(kD,      dim3(M_Q * CH2 / 4 / 256),  dim3(256), 0, stream, z, stats2, g2, b2, out);
}

// Round 21
// 132.363 us; speedup vs baseline: 1.0207x; 1.0207x over previous
//
#include <hip/hip_runtime.h>
#include <hip/hip_bf16.h>

#define N_SUP 16384
#define M_Q   4096
#define TV    27
#define CIN   41
#define CINP  44          // padded LDS stride (176 B, 16B-aligned rows)
#define CH1   864
#define CH2   128
#define CAP   1024
#define NB    12          // bins per xy axis (width 50/12 = 4.17 >= 4)
#define NSL   9           // candidate-scan slices per voxel (27*9 = 243 threads)

// kC split-K tiling: 32x128 tile, 4x4/thread, BK=24, 4 K-chunks of 216 -> grid 512
#define KC_BK  24
#define KC_KS  216
#define KC_NCH 4

// grid offset value for axis-index 0/1/2 : linspace(-R+R/NV, R-R/NV, 3) = {-1.3333334, 0, +1.3333334}
__device__ __forceinline__ float gsel(int i){
  const float GOFF = (float)(-2.0 + 2.0 / 3.0);   // -1.3333334f (matches f32 linspace endpoint)
  return (i == 0) ? GOFF : ((i == 2) ? -GOFF : 0.0f);
}

__device__ __forceinline__ int binOf(float x){
  int b = (int)(x * (float)(NB / 50.0));
  return (b < 0) ? 0 : ((b > NB - 1) ? NB - 1 : b);
}

// branchless 3-deep insert of u64 key (keeps k0 <= k1 <= k2)
__device__ __forceinline__ void insK(unsigned long long key,
                                     unsigned long long& k0,
                                     unsigned long long& k1,
                                     unsigned long long& k2){
  bool b0 = key < k0, b1 = key < k1, b2 = key < k2;
  k2 = b1 ? k1 : (b2 ? key : k2);
  k1 = b0 ? k0 : (b1 ? key : k1);
  k0 = b0 ? key : k0;
}

// ---------------- Kernel Pre: w1/w2 transpose + support-point bin count (fused) ----------------
__global__ void kPre(const float* __restrict__ w1, float* __restrict__ w1T,
                     const float* __restrict__ w2, float* __restrict__ w2T,
                     const float* __restrict__ sup_xyz, int* __restrict__ counts)
{
  int idx = blockIdx.x * 256 + threadIdx.x;
  if (idx < N_SUP) {
    float x = sup_xyz[3*idx], y = sup_xyz[3*idx+1];
    atomicAdd(&counts[binOf(x) * NB + binOf(y)], 1);
  }
  if (idx < CIN * CH1) {
    int k = idx / CH1, t = idx % CH1;
    w1T[idx] = w1[(size_t)t * CIN + k];
  }
  int j = idx - CIN * CH1;
  if (j >= 0 && j < CH1 * CH2) {
    int k = j / CH2, c = j % CH2;
    w2T[j] = w2[(size_t)c * CH1 + k];
  }
}

__global__ void kScan(const int* __restrict__ counts, int* __restrict__ starts, int* __restrict__ cursor)
{
  __shared__ int sc[NB*NB];
  int t = threadIdx.x;
  if (t < NB*NB) sc[t] = counts[t];
  __syncthreads();
  if (t == 0) {
    int acc = 0;
    for (int b = 0; b < NB*NB; b++) { int c = sc[b]; sc[b] = acc; acc += c; }
  }
  __syncthreads();
  if (t < NB*NB) { starts[t] = sc[t]; cursor[t] = sc[t]; }
  if (t == NB*NB) starts[NB*NB] = N_SUP;
}

__global__ void kScatter(const float* __restrict__ sup_xyz, int* __restrict__ cursor,
                         float4* __restrict__ pxyzs)
{
  int i = blockIdx.x * 256 + threadIdx.x;
  if (i < N_SUP) {
    float x = sup_xyz[3*i], y = sup_xyz[3*i+1], z = sup_xyz[3*i+2];
    int b = binOf(x) * NB + binOf(y);
    int p = atomicAdd(&cursor[b], 1);
    pxyzs[p] = make_float4(x, y, z, __uint_as_float((unsigned)i));
  }
}

// ---------------- Kernel A12: bin-pruned cube filter + per-voxel 3NN (guarded insert) ----------------
// (round-17/19 proven version: flat scan, bit-exact _rn distance, 9 slices/voxel, packed loads)
__global__ __launch_bounds__(256) void kA12(const float4* __restrict__ pxyzs,
                                            const int*   __restrict__ starts,
                                            const float* __restrict__ new_xyz,
                                            float* __restrict__ nnD,
                                            int*   __restrict__ nnGI)
{
  __shared__ float4 cxyz[CAP];                 // filtered candidates (.w = sid bits)
  __shared__ unsigned long long sk[TV][NSL][3];
  __shared__ int s_cnt;

  const int m   = blockIdx.x;
  const int tid = threadIdx.x;
  if (tid == 0) s_cnt = 0;
  __syncthreads();

  const float qx = new_xyz[m*3+0];
  const float qy = new_xyz[m*3+1];
  const float qz = new_xyz[m*3+2];

  // ---- phase 1: cube filter over <=3x3 bins (z-test vacuous: |dz|<4 always) ----
  const int bx0 = binOf(qx - 4.0f), bx1 = binOf(qx + 4.0f);
  const int by0 = binOf(qy - 4.0f), by1 = binOf(qy + 4.0f);
  for (int bx = bx0; bx <= bx1; bx++) {
    const int beg = starts[bx * NB + by0];
    const int end = starts[bx * NB + by1 + 1];
    for (int i = beg + tid; i < end; i += 256) {
      float4 pt = pxyzs[i];
      if (fabsf(__fsub_rn(pt.x, qx)) <= 4.0f && fabsf(__fsub_rn(pt.y, qy)) <= 4.0f) {
        int p = atomicAdd(&s_cnt, 1);
        if (p < CAP) cxyz[p] = pt;
      }
    }
  }
  __syncthreads();
  const int cnt = (s_cnt < CAP) ? s_cnt : CAP;

  // ---- phase 2a: strided scan, 9 threads per voxel, guarded insert ----
  const int v = tid / NSL, j = tid % NSL;      // 243 active threads
  if (v < TV) {
    const float gx = qx + gsel(v / 9);
    const float gy = qy + gsel((v / 3) % 3);
    const float gz = qz + gsel(v % 3);
    unsigned long long k0 = ~0ull, k1 = ~0ull, k2 = ~0ull;
    float k2df = __uint_as_float(0xFFFFFFFFu);   // NaN sentinel -> insert path until 3 found
    for (int c = j; c < cnt; c += NSL) {
      float4 f4 = cxyz[c];
      float dx = __fsub_rn(gx, f4.x);
      float dy = __fsub_rn(gy, f4.y);
      float dz = __fsub_rn(gz, f4.z);
      // forbid FMA contraction: must match numpy f32 (mul, mul, add, mul, add)
      float dd = __fadd_rn(__fadd_rn(__fmul_rn(dx,dx), __fmul_rn(dy,dy)), __fmul_rn(dz,dz));
      if (!(dd > k2df)) {                        // fast reject; == still takes insert (tie by sid)
        unsigned long long key = ((unsigned long long)__float_as_uint(dd) << 32)
                               | (unsigned long long)__float_as_uint(f4.w); // low = sid
        insK(key, k0, k1, k2);
        k2df = __uint_as_float((unsigned)(k2 >> 32));
      }
    }
    sk[v][j][0] = k0; sk[v][j][1] = k1; sk[v][j][2] = k2;
  }
  __syncthreads();

  // ---- phase 2b: merge 9x3 keys per voxel + dump (d,gi) (threads 0..26) ----
  if (tid < TV) {
    const int vv = tid;
    unsigned long long k0 = ~0ull, k1 = ~0ull, k2 = ~0ull;
    #pragma unroll
    for (int jj = 0; jj < NSL; jj++) {
      insK(sk[vv][jj][0], k0, k1, k2);
      insK(sk[vv][jj][1], k0, k1, k2);
      insK(sk[vv][jj][2], k0, k1, k2);
    }
    const int base = m * TV + vv;
    if (cnt > 0) {
      unsigned long long ks[3] = {k0, k1, k2};
      #pragma unroll
      for (int r = 0; r < 3; r++) {
        unsigned db = (unsigned)(ks[r] >> 32);
        bool ok = (db != 0xFFFFFFFFu);
        nnD[base*3+r]  = ok ? __uint_as_float(db) : 1e10f;
        nnGI[base*3+r] = ok ? (int)(unsigned)(ks[r] & 0xFFFFFFFFull) : 0;
      }
    } else {
      #pragma unroll
      for (int r = 0; r < 3; r++) { nnD[base*3+r] = -1.0f; nnGI[base*3+r] = 0; }
    }
  }
}

// ---------------- Kernel A3: weights + local_xyz + interp + conv1 (8 queries/block) + BN1 stats ----------------
__global__ __launch_bounds__(256) void kA3(const float* __restrict__ sup_feat,
                                           const float* __restrict__ sup_xyz,
                                           const float* __restrict__ new_xyz,
                                           const float* __restrict__ nnD,
                                           const int*   __restrict__ nnGI,
                                           const float* __restrict__ w1T,
                                           float* __restrict__ y1,
                                           float* __restrict__ stats1)   // [8][2*CH1]
{
  __shared__ float s_feats[8][TV][CINP];  // 38,016 B (rows 16B-aligned)
  __shared__ float s_w[8][TV][3];
  __shared__ int   s_gi[8][TV][3];

  const int m0  = blockIdx.x * 8;
  const int tid = threadIdx.x;

  // per-(q,v) thread: weights + local_xyz (216 threads)
  if (tid < 8*TV) {
    const int q = tid / TV, vv = tid % TV;
    const int m = m0 + q;
    const int base = m * TV + vv;
    float d[3]; int gi[3];
    #pragma unroll
    for (int r = 0; r < 3; r++) { d[r] = nnD[base*3+r]; gi[r] = nnGI[base*3+r]; }
    #pragma unroll
    for (int r = 0; r < 3; r++) s_gi[q][vv][r] = gi[r];
    if (d[0] < 0.0f) {                           // empty query: zero weights + zero local
      #pragma unroll
      for (int r = 0; r < 3; r++) s_w[q][vv][r] = 0.0f;
      #pragma unroll
      for (int jj = 0; jj < 9; jj++) s_feats[q][vv][32 + jj] = 0.0f;
    } else {
      float r0 = 1.0f / (d[0] + 1e-8f);
      float r1 = 1.0f / (d[1] + 1e-8f);
      float r2 = 1.0f / (d[2] + 1e-8f);
      float den = fmaxf(r0 + r1 + r2, 1e-8f);
      s_w[q][vv][0] = r0 / den; s_w[q][vv][1] = r1 / den; s_w[q][vv][2] = r2 / den;
      const float gx = new_xyz[m*3+0] + gsel(vv / 9);
      const float gy = new_xyz[m*3+1] + gsel((vv / 3) % 3);
      const float gz = new_xyz[m*3+2] + gsel(vv % 3);
      #pragma unroll
      for (int r = 0; r < 3; r++) {
        bool ok = (d[r] != 1e10f);
        s_feats[q][vv][32 + r*3 + 0] = ok ? (gx - sup_xyz[gi[r]*3 + 0]) : 0.0f;
        s_feats[q][vv][32 + r*3 + 1] = ok ? (gy - sup_xyz[gi[r]*3 + 1]) : 0.0f;
        s_feats[q][vv][32 + r*3 + 2] = ok ? (gz - sup_xyz[gi[r]*3 + 2]) : 0.0f;
      }
    }
  }
  __syncthreads();

  // interp, float4: 8*27*8 = 1728 float4 elements
  const float4* sf4 = (const float4*)sup_feat;
  for (int t = tid; t < 8*TV*8; t += 256) {
    const int q = t / (TV*8), rem = t % (TV*8);
    const int v = rem >> 3, g = rem & 7;        // 8 float4 groups = 32 channels
    float4 a = sf4[s_gi[q][v][0]*8 + g];
    float4 b = sf4[s_gi[q][v][1]*8 + g];
    float4 c = sf4[s_gi[q][v][2]*8 + g];
    float w0 = s_w[q][v][0], w1_ = s_w[q][v][1], w2_ = s_w[q][v][2];
    float4 o;
    o.x = w0*a.x + w1_*b.x + w2_*c.x;
    o.y = w0*a.y + w1_*b.y + w2_*c.y;
    o.z = w0*a.z + w1_*b.z + w2_*c.z;
    o.w = w0*a.w + w1_*b.w + w2_*c.w;
    *(float4*)&s_feats[q][v][g*4] = o;
  }
  __syncthreads();

  const int copy = (blockIdx.x & 7) * 2 * CH1;   // spread stat atomics over 8 copies
  for (int t = tid; t < CH1; t += 256) {
    const int v = t >> 5;
    float acc[8];
    #pragma unroll
    for (int q = 0; q < 8; q++) acc[q] = 0.0f;
    for (int k = 0; k < CIN; k++) {
      float w = w1T[k * CH1 + t];
      #pragma unroll
      for (int q = 0; q < 8; q++) acc[q] += s_feats[q][v][k] * w;
    }
    float s = 0.0f, ss = 0.0f;
    #pragma unroll
    for (int q = 0; q < 8; q++) {
      y1[(size_t)(m0 + q) * CH1 + t] = acc[q];
      s += acc[q]; ss += acc[q] * acc[q];
    }
    atomicAdd(&stats1[copy + t],       s);
    atomicAdd(&stats1[copy + CH1 + t], ss);
  }
}

// ---------------- Kernel C: BN1-fused split-K GEMM (kS fused), 32x128 tile, 4x4/thread, grid 512 ----------------
__global__ __launch_bounds__(256) void kC(const float* __restrict__ y1,
                                          const float* __restrict__ stats1,   // [8][2*CH1]
                                          const float* __restrict__ g1,
                                          const float* __restrict__ b1,
                                          const float* __restrict__ w2T,
                                          float* __restrict__ zpart)   // [4][M_Q][CH2]
{
  __shared__ float As[KC_BK][36];      // [k][row], stride 36 (144 B, 16B-aligned rows)
  __shared__ float Bs[KC_BK][CH2];     // 12 KB
  __shared__ float lsc[KC_KS], lsh[KC_KS];

  const int tid = threadIdx.x;
  const int mb  = blockIdx.x & 127;
  const int ch  = blockIdx.x >> 7;
  const int m0  = mb * 32;
  const int kb  = ch * KC_KS;

  // fused kS: BN1 scale/shift for this chunk's 216 channels (sums 8 stat copies)
  for (int t = tid; t < KC_KS; t += 256) {
    const int c = kb + t;
    float s = 0.0f, ssq = 0.0f;
    #pragma unroll
    for (int k = 0; k < 8; k++) {
      s   += stats1[k * 2 * CH1 + c];
      ssq += stats1[k * 2 * CH1 + CH1 + c];
    }
    float mu  = s  * (1.0f / M_Q);
    float var = ssq * (1.0f / M_Q) - mu * mu;
    float r   = 1.0f / sqrtf(var + 1e-5f);
    float gg = g1[c];
    lsc[t] = r * gg;
    lsh[t] = b1[c] - mu * r * gg;
  }

  const int ar = tid >> 3;          // 0..31 A-tile row
  const int ac = (tid & 7) * 3;     // 0..21 A-tile k-offset (3 consecutive)
  const int ty = tid >> 5;          // 0..7  -> rows ty*4..+3
  const int tx = tid & 31;          // 0..31 -> cols tx*4..+3

  // prefetch tile 0
  float pa0, pa1, pa2; float4 pb[3];
  {
    const float* yr = &y1[(size_t)(m0 + ar) * CH1 + kb + ac];
    pa0 = yr[0]; pa1 = yr[1]; pa2 = yr[2];
    #pragma unroll
    for (int jj = 0; jj < 3; jj++) {
      int fid = tid + jj * 256; int kk = fid >> 5, c4 = (fid & 31) * 4;
      pb[jj] = *(const float4*)&w2T[(size_t)(kb + kk) * CH2 + c4];
    }
  }

  float acc[4][4];
  #pragma unroll
  for (int i = 0; i < 4; i++)
    #pragma unroll
    for (int jj = 0; jj < 4; jj++) acc[i][jj] = 0.0f;

  for (int kt = 0; kt < KC_KS / KC_BK; kt++) {
    __syncthreads();                       // previous tile consumed; covers lsc/lsh at kt=0
    const int kl = kt * KC_BK + ac;
    As[ac  ][ar] = fmaxf(pa0 * lsc[kl  ] + lsh[kl  ], 0.0f);
    As[ac+1][ar] = fmaxf(pa1 * lsc[kl+1] + lsh[kl+1], 0.0f);
    As[ac+2][ar] = fmaxf(pa2 * lsc[kl+2] + lsh[kl+2], 0.0f);
    #pragma unroll
    for (int jj = 0; jj < 3; jj++) {
      int fid = tid + jj * 256; int kk = fid >> 5, c4 = (fid & 31) * 4;
      *(float4*)&Bs[kk][c4] = pb[jj];
    }
    __syncthreads();
    if (kt + 1 < KC_KS / KC_BK) {          // prefetch next tile (overlaps compute)
      const float* yr = &y1[(size_t)(m0 + ar) * CH1 + kb + (kt+1) * KC_BK + ac];
      pa0 = yr[0]; pa1 = yr[1]; pa2 = yr[2];
      #pragma unroll
      for (int jj = 0; jj < 3; jj++) {
        int fid = tid + jj * 256; int kk = fid >> 5, c4 = (fid & 31) * 4;
        pb[jj] = *(const float4*)&w2T[(size_t)(kb + (kt+1) * KC_BK + kk) * CH2 + c4];
      }
    }
    #pragma unroll
    for (int kk = 0; kk < KC_BK; kk++) {
      float4 av = *(const float4*)&As[kk][ty*4];
      float4 bv = *(const float4*)&Bs[kk][tx*4];
      acc[0][0] += av.x*bv.x; acc[0][1] += av.x*bv.y; acc[0][2] += av.x*bv.z; acc[0][3] += av.x*bv.w;
      acc[1][0] += av.y*bv.x; acc[1][1] += av.y*bv.y; acc[1][2] += av.y*bv.z; acc[1][3] += av.y*bv.w;
      acc[2][0] += av.z*bv.x; acc[2][1] += av.z*bv.y; acc[2][2] += av.z*bv.z; acc[2][3] += av.z*bv.w;
      acc[3][0] += av.w*bv.x; acc[3][1] += av.w*bv.y; acc[3][2] += av.w*bv.z; acc[3][3] += av.w*bv.w;
    }
  }

  float* zp = zpart + (size_t)ch * M_Q * CH2;
  #pragma unroll
  for (int i = 0; i < 4; i++) {
    *(float4*)&zp[(size_t)(m0 + ty*4 + i) * CH2 + tx*4] =
        make_float4(acc[i][0], acc[i][1], acc[i][2], acc[i][3]);
  }
}

// ---------------- Kernel Z: sum split-K partials -> z, BN2 stats (grid 512) ----------------
__global__ void kZ(const float* __restrict__ zpart,
                   float* __restrict__ z,
                   float* __restrict__ stats2)   // [8][256]
{
  const int tid = threadIdx.x;
  const int c = tid & 127, h = tid >> 7;
  const int m0 = blockIdx.x * 8 + h * 4;
  float s = 0.0f, ss = 0.0f;
  for (int r = 0; r < 4; r++) {
    size_t off = (size_t)(m0 + r) * CH2 + c;
    float v = zpart[off]
            + zpart[off + (size_t)M_Q*CH2]
            + zpart[off + (size_t)2*M_Q*CH2]
            + zpart[off + (size_t)3*M_Q*CH2];
    z[off] = v;
    s += v; ss += v * v;
  }
  const int copy = (blockIdx.x & 7) * 256;
  atomicAdd(&stats2[copy + c],       s);
  atomicAdd(&stats2[copy + 128 + c], ss);
}

// ---------------- Kernel D: BN2 apply + ReLU -> f32 out (float4) ----------------
__global__ void kD(const float* __restrict__ z,
                   const float* __restrict__ stats2,   // [8][256]
                   const float* __restrict__ g2,
                   const float* __restrict__ b2,
                   float* __restrict__ out)
{
  int t4 = blockIdx.x * 256 + threadIdx.x;
  if (t4 >= M_Q * CH2 / 4) return;
  int c = (t4 & 31) * 4;
  float4 zv = *(const float4*)&z[(size_t)t4 * 4];
  float4 sv = make_float4(0,0,0,0), qv = make_float4(0,0,0,0);
  #pragma unroll
  for (int k = 0; k < 8; k++) {
    float4 a = *(const float4*)&stats2[k * 256 + c];
    float4 b = *(const float4*)&stats2[k * 256 + 128 + c];
    sv.x += a.x; sv.y += a.y; sv.z += a.z; sv.w += a.w;
    qv.x += b.x; qv.y += b.y; qv.z += b.z; qv.w += b.w;
  }
  float4 gv = *(const float4*)&g2[c];
  float4 bv = *(const float4*)&b2[c];
  float4 o;
  {
    float mu = sv.x * (1.0f/M_Q), var = qv.x * (1.0f/M_Q) - mu*mu;
    o.x = fmaxf((zv.x - mu) * (1.0f/sqrtf(var + 1e-5f)) * gv.x + bv.x, 0.0f);
  }
  {
    float mu = sv.y * (1.0f/M_Q), var = qv.y * (1.0f/M_Q) - mu*mu;
    o.y = fmaxf((zv.y - mu) * (1.0f/sqrtf(var + 1e-5f)) * gv.y + bv.y, 0.0f);
  }
  {
    float mu = sv.z * (1.0f/M_Q), var = qv.z * (1.0f/M_Q) - mu*mu;
    o.z = fmaxf((zv.z - mu) * (1.0f/sqrtf(var + 1e-5f)) * gv.z + bv.z, 0.0f);
  }
  {
    float mu = sv.w * (1.0f/M_Q), var = qv.w * (1.0f/M_Q) - mu*mu;
    o.w = fmaxf((zv.w - mu) * (1.0f/sqrtf(var + 1e-5f)) * gv.w + bv.w, 0.0f);
  }
  *(float4*)&out[(size_t)t4 * 4] = o;
}

extern "C" void kernel_launch(void* const* d_in, const int* in_sizes, int n_in,
                              void* d_out, int out_size, void* d_ws, size_t ws_size,
                              hipStream_t stream)
{
  const float* sup_xyz  = (const float*)d_in[0];
  const float* sup_feat = (const float*)d_in[1];
  const float* new_xyz  = (const float*)d_in[2];
  const float* w1       = (const float*)d_in[3];
  const float* g1       = (const float*)d_in[4];
  const float* b1       = (const float*)d_in[5];
  const float* w2       = (const float*)d_in[6];
  const float* g2       = (const float*)d_in[7];
  const float* b2       = (const float*)d_in[8];
  float* out = (float*)d_out;

  char* ws = (char*)d_ws;
  float*  y1     = (float*)(ws);                      // 14,155,776 B
  float*  z      = (float*)(ws + 14155776);           //  2,097,152 B (aliased by w1T early)
  float*  w2T    = (float*)(ws + 16252928);           //    442,368 B
  float*  stats1 = (float*)(ws + 16695296);           // 8 x 1728 f32 = 55,296 B
  float*  stats2 = (float*)(ws + 16750592);           // 8 x  256 f32 =  8,192 B
  int*    counts = (int*)  (ws + 16758784);           //        576 B
  int*    cursor = (int*)  (ws + 16759360);           //        576 B
  int*    starts = (int*)  (ws + 16759936);           //        580 B (pad to 16B)
  float4* pxyzs  = (float4*)(ws + 16760528);          //    262,144 B (16B-aligned)
  float*  nnD    = (float*)(ws + 17022672);           //  1,327,104 B
  int*    nnGI   = (int*)  (ws + 18349776);           //  1,327,104 B
  // zpart (4 x 2,097,152 B = 8,388,608 B) aliases nnD/nnGI (dead after kA3) and
  // extends past them; total ws footprint = 17,022,672 + 8,388,608 = 25,411,280 B.
  float*  zpart  = (float*)(ws + 17022672);
  // w1T (141,696 B) aliases z: kA3 (last reader) runs before kC/kZ touch z.
  float*  w1T    = z;

  // zero stats1 + stats2 + counts + cursor in one contiguous memset
  hipMemsetAsync(stats1, 0, 55296 + 8192 + 576 + 576, stream);

  const int PRE_TOT = CIN*CH1 + CH1*CH2;              // covers N_SUP too
  hipLaunchKernelGGL(kPre,    dim3((PRE_TOT + 255) / 256), dim3(256), 0, stream, w1, w1T, w2, w2T, sup_xyz, counts);
  hipLaunchKernelGGL(kScan,   dim3(1),                    dim3(256), 0, stream, counts, starts, cursor);
  hipLaunchKernelGGL(kScatter,dim3((N_SUP + 255) / 256),  dim3(256), 0, stream, sup_xyz, cursor, pxyzs);
  hipLaunchKernelGGL(kA12,    dim3(M_Q),                  dim3(256), 0, stream, pxyzs, starts, new_xyz, nnD, nnGI);
  hipLaunchKernelGGL(kA3,     dim3(M_Q / 8),              dim3(256), 0, stream, sup_feat, sup_xyz, new_xyz, nnD, nnGI, w1T, y1, stats1);
  hipLaunchKernelGGL(kC,      dim3(128 * KC_NCH),         dim3(256), 0, stream, y1, stats1, g1, b1, w2T, zpart);
  hipLaunchKernelGGL(kZ,      dim3(M_Q / 8),              dim3(256), 0, stream, zpart, z, stats2);
  hipLaunchKernelGGL(kD,      dim3(M_Q * CH2 / 4 / 256),  dim3(256), 0, stream, z, stats2, g2, b2, out);
}